// Round 1
// baseline (506.782 us; speedup 1.0000x reference)
//
#include <hip/hip_runtime.h>
#include <hip/hip_bf16.h>
#include <stdint.h>

#define N_NODES 100000
#define N_EDGES 600000
#define D 128
#define EPS 1e-5f

typedef __attribute__((ext_vector_type(8))) short short8;
typedef __attribute__((ext_vector_type(16))) float floatx16;

// ---------- helpers ----------

__device__ __forceinline__ uint32_t pack_bf16_rne(float lo, float hi) {
    // round-to-nearest-even f32->bf16, packed pair (lo in low 16)
    uint32_t ul = __builtin_bit_cast(uint32_t, lo);
    uint32_t uh = __builtin_bit_cast(uint32_t, hi);
    ul += 0x7fffu + ((ul >> 16) & 1u);
    uh += 0x7fffu + ((uh >> 16) & 1u);
    return (ul >> 16) | (uh & 0xffff0000u);
}

__device__ __forceinline__ unsigned short f32_to_bf16_rne(float f) {
    uint32_t u = __builtin_bit_cast(uint32_t, f);
    u += 0x7fffu + ((u >> 16) & 1u);
    return (unsigned short)(u >> 16);
}

// ---------- weight re-layout into 32x32x16 MFMA B-fragment order ----------
// frag element (s, t, lane, j)  <->  w[k = s*16 + (lane>>5)*8 + j][n = t*32 + (lane&31)]
// linear index = (((s*4 + t)*64) + lane)*8 + j     (K x 128 matrix, K = 256 or 128)
__global__ void prep_weights(const float* __restrict__ w, unsigned short* __restrict__ out, int K) {
    int idx = blockIdx.x * blockDim.x + threadIdx.x;
    int total = K * 128;
    if (idx >= total) return;
    int j    = idx & 7;
    int lane = (idx >> 3) & 63;
    int t    = (idx >> 9) & 3;
    int s    = idx >> 11;
    int k = s * 16 + ((lane >> 5) << 3) + j;
    int n = t * 32 + (lane & 31);
    out[idx] = f32_to_bf16_rne(w[k * 128 + n]);
}

// ---------- message kernel: per wave, 64 edges (2 x M=32 groups) ----------
__launch_bounds__(256, 2)
__global__ void msg_kernel(const float* __restrict__ x,
                           const int* __restrict__ rowidx, const int* __restrict__ colidx,
                           const short8* __restrict__ w1f, const short8* __restrict__ w2f,
                           const float* __restrict__ b1, const float* __restrict__ b2,
                           float* __restrict__ agg) {
    __shared__ __align__(16) short h1[4][64 * 136];
    const int wave = threadIdx.x >> 6;
    const int lane = threadIdx.x & 63;
    const int l31  = lane & 31;
    const int half = lane >> 5;
    short* hl = h1[wave];

    const int ebase = (blockIdx.x * 4 + wave) * 64;
    const int eA = ebase + l31;
    const int eB = ebase + 32 + l31;
    const int eAc = min(eA, N_EDGES - 1);
    const int eBc = min(eB, N_EDGES - 1);
    const int rA = rowidx[eAc], cA = colidx[eAc];
    const int rB = rowidx[eBc], cB = colidx[eBc];

    const float* pArow = x + (size_t)rA * D + half * 8;
    const float* pAcol = x + (size_t)cA * D + half * 8;
    const float* pBrow = x + (size_t)rB * D + half * 8;
    const float* pBcol = x + (size_t)cB * D + half * 8;

    floatx16 acc[2][4];
#pragma unroll
    for (int g = 0; g < 2; ++g)
#pragma unroll
        for (int t = 0; t < 4; ++t) acc[g][t] = (floatx16)0.0f;

    // GEMM1: [64 x 256] @ [256 x 128], K in 16 steps of 16
#pragma unroll
    for (int s = 0; s < 16; ++s) {
        const float* pa = (s < 8) ? pArow : pAcol;
        const float* pb = (s < 8) ? pBrow : pBcol;
        const int off = (s & 7) * 16;
        float4 a0 = *(const float4*)(pa + off);
        float4 a1 = *(const float4*)(pa + off + 4);
        float4 c0 = *(const float4*)(pb + off);
        float4 c1 = *(const float4*)(pb + off + 4);
        union { short8 v; uint32_t u[4]; } fa, fb;
        fa.u[0] = pack_bf16_rne(a0.x, a0.y); fa.u[1] = pack_bf16_rne(a0.z, a0.w);
        fa.u[2] = pack_bf16_rne(a1.x, a1.y); fa.u[3] = pack_bf16_rne(a1.z, a1.w);
        fb.u[0] = pack_bf16_rne(c0.x, c0.y); fb.u[1] = pack_bf16_rne(c0.z, c0.w);
        fb.u[2] = pack_bf16_rne(c1.x, c1.y); fb.u[3] = pack_bf16_rne(c1.z, c1.w);
#pragma unroll
        for (int t = 0; t < 4; ++t) {
            short8 wf = w1f[(s * 4 + t) * 64 + lane];
            acc[0][t] = __builtin_amdgcn_mfma_f32_32x32x16_bf16(fa.v, wf, acc[0][t], 0, 0, 0);
            acc[1][t] = __builtin_amdgcn_mfma_f32_32x32x16_bf16(fb.v, wf, acc[1][t], 0, 0, 0);
        }
    }

    // bias + ReLU + bf16, C-layout -> LDS row-major [64][136]
    float bias1[4];
#pragma unroll
    for (int t = 0; t < 4; ++t) bias1[t] = b1[t * 32 + l31];

#pragma unroll
    for (int g = 0; g < 2; ++g)
#pragma unroll
        for (int t = 0; t < 4; ++t)
#pragma unroll
            for (int r = 0; r < 16; ++r) {
                int m = (r & 3) + 8 * (r >> 2) + 4 * half + 32 * g;
                float v = acc[g][t][r] + bias1[t];
                v = fmaxf(v, 0.0f);
                hl[m * 136 + t * 32 + l31] = (short)f32_to_bf16_rne(v);
            }

    __syncthreads();

    // GEMM2: [64 x 128] @ [128 x 128], K in 8 steps
    floatx16 acc2[2][4];
#pragma unroll
    for (int g = 0; g < 2; ++g)
#pragma unroll
        for (int t = 0; t < 4; ++t) acc2[g][t] = (floatx16)0.0f;

#pragma unroll
    for (int s = 0; s < 8; ++s) {
        short8 aA = *(const short8*)(hl + l31 * 136 + s * 16 + half * 8);
        short8 aB = *(const short8*)(hl + (l31 + 32) * 136 + s * 16 + half * 8);
#pragma unroll
        for (int t = 0; t < 4; ++t) {
            short8 wf = w2f[(s * 4 + t) * 64 + lane];
            acc2[0][t] = __builtin_amdgcn_mfma_f32_32x32x16_bf16(aA, wf, acc2[0][t], 0, 0, 0);
            acc2[1][t] = __builtin_amdgcn_mfma_f32_32x32x16_bf16(aB, wf, acc2[1][t], 0, 0, 0);
        }
    }

    // bias + scatter-add (atomics); instr covers 2 rows x 32 contiguous cols
    float bias2[4];
#pragma unroll
    for (int t = 0; t < 4; ++t) bias2[t] = b2[t * 32 + l31];

#pragma unroll
    for (int g = 0; g < 2; ++g) {
        int colv = g ? cB : cA;  // col[ebase + 32g + l31], same in both halves
#pragma unroll
        for (int r = 0; r < 16; ++r) {
            int m = (r & 3) + 8 * (r >> 2) + 4 * half;
            int e = ebase + 32 * g + m;
            int cm = __shfl(colv, m, 32);
            if (e < N_EDGES) {
                float* dst = agg + (size_t)cm * D + l31;
#pragma unroll
                for (int t = 0; t < 4; ++t)
                    unsafeAtomicAdd(dst + t * 32, acc2[g][t][r] + bias2[t]);
            }
        }
    }
}

// ---------- update kernel: GEMMs + fused LayerNorm + residual ----------
__launch_bounds__(256, 2)
__global__ void upd_kernel(const float* __restrict__ x, const float* __restrict__ agg,
                           const short8* __restrict__ w1f, const short8* __restrict__ w2f,
                           const float* __restrict__ b1, const float* __restrict__ b2,
                           const float* __restrict__ gamma, const float* __restrict__ beta,
                           float* __restrict__ out) {
    __shared__ __align__(16) short h1[4][64 * 136];
    const int wave = threadIdx.x >> 6;
    const int lane = threadIdx.x & 63;
    const int l31  = lane & 31;
    const int half = lane >> 5;
    short* hl = h1[wave];

    const int nbase = (blockIdx.x * 4 + wave) * 64;
    const int nA = min(nbase + l31, N_NODES - 1);
    const int nB = min(nbase + 32 + l31, N_NODES - 1);

    const float* pAx = x   + (size_t)nA * D + half * 8;
    const float* pAa = agg + (size_t)nA * D + half * 8;
    const float* pBx = x   + (size_t)nB * D + half * 8;
    const float* pBa = agg + (size_t)nB * D + half * 8;

    floatx16 acc[2][4];
#pragma unroll
    for (int g = 0; g < 2; ++g)
#pragma unroll
        for (int t = 0; t < 4; ++t) acc[g][t] = (floatx16)0.0f;

#pragma unroll
    for (int s = 0; s < 16; ++s) {
        const float* pa = (s < 8) ? pAx : pAa;
        const float* pb = (s < 8) ? pBx : pBa;
        const int off = (s & 7) * 16;
        float4 a0 = *(const float4*)(pa + off);
        float4 a1 = *(const float4*)(pa + off + 4);
        float4 c0 = *(const float4*)(pb + off);
        float4 c1 = *(const float4*)(pb + off + 4);
        union { short8 v; uint32_t u[4]; } fa, fb;
        fa.u[0] = pack_bf16_rne(a0.x, a0.y); fa.u[1] = pack_bf16_rne(a0.z, a0.w);
        fa.u[2] = pack_bf16_rne(a1.x, a1.y); fa.u[3] = pack_bf16_rne(a1.z, a1.w);
        fb.u[0] = pack_bf16_rne(c0.x, c0.y); fb.u[1] = pack_bf16_rne(c0.z, c0.w);
        fb.u[2] = pack_bf16_rne(c1.x, c1.y); fb.u[3] = pack_bf16_rne(c1.z, c1.w);
#pragma unroll
        for (int t = 0; t < 4; ++t) {
            short8 wf = w1f[(s * 4 + t) * 64 + lane];
            acc[0][t] = __builtin_amdgcn_mfma_f32_32x32x16_bf16(fa.v, wf, acc[0][t], 0, 0, 0);
            acc[1][t] = __builtin_amdgcn_mfma_f32_32x32x16_bf16(fb.v, wf, acc[1][t], 0, 0, 0);
        }
    }

    float bias1[4];
#pragma unroll
    for (int t = 0; t < 4; ++t) bias1[t] = b1[t * 32 + l31];

#pragma unroll
    for (int g = 0; g < 2; ++g)
#pragma unroll
        for (int t = 0; t < 4; ++t)
#pragma unroll
            for (int r = 0; r < 16; ++r) {
                int m = (r & 3) + 8 * (r >> 2) + 4 * half + 32 * g;
                float v = acc[g][t][r] + bias1[t];
                v = fmaxf(v, 0.0f);
                hl[m * 136 + t * 32 + l31] = (short)f32_to_bf16_rne(v);
            }

    __syncthreads();

    floatx16 acc2[2][4];
#pragma unroll
    for (int g = 0; g < 2; ++g)
#pragma unroll
        for (int t = 0; t < 4; ++t) acc2[g][t] = (floatx16)0.0f;

#pragma unroll
    for (int s = 0; s < 8; ++s) {
        short8 aA = *(const short8*)(hl + l31 * 136 + s * 16 + half * 8);
        short8 aB = *(const short8*)(hl + (l31 + 32) * 136 + s * 16 + half * 8);
#pragma unroll
        for (int t = 0; t < 4; ++t) {
            short8 wf = w2f[(s * 4 + t) * 64 + lane];
            acc2[0][t] = __builtin_amdgcn_mfma_f32_32x32x16_bf16(aA, wf, acc2[0][t], 0, 0, 0);
            acc2[1][t] = __builtin_amdgcn_mfma_f32_32x32x16_bf16(aB, wf, acc2[1][t], 0, 0, 0);
        }
    }

    // fused LayerNorm + residual. Row m lives in one 32-lane half; butterfly-reduce.
    float g4[4], be4[4], bias2[4];
#pragma unroll
    for (int t = 0; t < 4; ++t) {
        g4[t]    = gamma[t * 32 + l31];
        be4[t]   = beta[t * 32 + l31];
        bias2[t] = b2[t * 32 + l31];
    }

#pragma unroll
    for (int g = 0; g < 2; ++g) {
#pragma unroll
        for (int r = 0; r < 16; ++r) {
            float hv[4];
            float s1 = 0.0f, s2 = 0.0f;
#pragma unroll
            for (int t = 0; t < 4; ++t) {
                hv[t] = acc2[g][t][r] + bias2[t];
                s1 += hv[t];
                s2 += hv[t] * hv[t];
            }
#pragma unroll
            for (int mask = 1; mask < 32; mask <<= 1) {
                s1 += __shfl_xor(s1, mask);
                s2 += __shfl_xor(s2, mask);
            }
            float mean = s1 * (1.0f / 128.0f);
            float var  = s2 * (1.0f / 128.0f) - mean * mean;
            float rs   = rsqrtf(var + EPS);
            int m = (r & 3) + 8 * (r >> 2) + 4 * half;
            int node = nbase + 32 * g + m;
            if (node < N_NODES) {
                const float* xr = x + (size_t)node * D + l31;
                float* orow = out + (size_t)node * D + l31;
#pragma unroll
                for (int t = 0; t < 4; ++t) {
                    float v = (hv[t] - mean) * rs * g4[t] + be4[t] + xr[t * 32];
                    orow[t * 32] = v;
                }
            }
        }
    }
}

// ---------- launch ----------
extern "C" void kernel_launch(void* const* d_in, const int* in_sizes, int n_in,
                              void* d_out, int out_size, void* d_ws, size_t ws_size,
                              hipStream_t stream) {
    const float* x     = (const float*)d_in[0];
    const int*   edge  = (const int*)d_in[1];
    const float* w_m1  = (const float*)d_in[2];
    const float* b_m1  = (const float*)d_in[3];
    const float* w_m2  = (const float*)d_in[4];
    const float* b_m2  = (const float*)d_in[5];
    const float* w_u1  = (const float*)d_in[6];
    const float* b_u1  = (const float*)d_in[7];
    const float* w_u2  = (const float*)d_in[8];
    const float* b_u2  = (const float*)d_in[9];
    const float* gamma = (const float*)d_in[10];
    const float* beta  = (const float*)d_in[11];
    float* out = (float*)d_out;

    char* ws = (char*)d_ws;
    float* agg = (float*)ws;
    const size_t aggBytes = (size_t)N_NODES * D * sizeof(float);
    unsigned short* wm1f = (unsigned short*)(ws + aggBytes);
    unsigned short* wm2f = wm1f + 256 * 128;
    unsigned short* wu1f = wm2f + 128 * 128;
    unsigned short* wu2f = wu1f + 256 * 128;

    hipMemsetAsync(agg, 0, aggBytes, stream);
    prep_weights<<<(256 * 128 + 255) / 256, 256, 0, stream>>>(w_m1, wm1f, 256);
    prep_weights<<<(128 * 128 + 255) / 256, 256, 0, stream>>>(w_m2, wm2f, 128);
    prep_weights<<<(256 * 128 + 255) / 256, 256, 0, stream>>>(w_u1, wu1f, 256);
    prep_weights<<<(128 * 128 + 255) / 256, 256, 0, stream>>>(w_u2, wu2f, 128);

    const int* rowi = edge;            // edge_index[0]
    const int* coli = edge + N_EDGES;  // edge_index[1]

    msg_kernel<<<(N_EDGES + 255) / 256, 256, 0, stream>>>(
        x, rowi, coli, (const short8*)wm1f, (const short8*)wm2f, b_m1, b_m2, agg);
    upd_kernel<<<(N_NODES + 255) / 256, 256, 0, stream>>>(
        x, agg, (const short8*)wu1f, (const short8*)wu2f, b_u1, b_u2, gamma, beta, out);
}